// Round 1
// baseline (1102.666 us; speedup 1.0000x reference)
//
#include <hip/hip_runtime.h>
#include <math.h>

#define BB  256
#define NXX 64
#define NYY 64
#define NPP 32
#define DD  256

// out layout: logits [B*3] | argc [B*D] | reg_loss [1]
#define OUT_ARGC   (BB * 3)
#define OUT_REG    (BB * 3 + BB * DD)

__device__ __forceinline__ float wave_reduce_sum(float v) {
    #pragma unroll
    for (int m = 32; m >= 1; m >>= 1) v += __shfl_xor(v, m, 64);
    return v;
}
__device__ __forceinline__ float wave_reduce_max(float v) {
    #pragma unroll
    for (int m = 32; m >= 1; m >>= 1) v = fmaxf(v, __shfl_xor(v, m, 64));
    return v;
}

__global__ __launch_bounds__(1024) void fused_graph_kernel(
    const float* __restrict__ feat,
    const int*   __restrict__ x_id,  const int* __restrict__ y_id,
    const int*   __restrict__ plo_id, const int* __restrict__ pro_id,
    const float* __restrict__ w1w,  const float* __restrict__ w1b,
    const float* __restrict__ w2w,  const float* __restrict__ w2b,
    const float* __restrict__ w6w,  const float* __restrict__ w6b,
    const float* __restrict__ w7w,  const float* __restrict__ w7b,
    const float* __restrict__ clsw, const float* __restrict__ clsb,
    float* __restrict__ out)
{
    const int b    = blockIdx.x;
    const int tid  = threadIdx.x;
    const int wave = tid >> 6;
    const int lane = tid & 63;

    __shared__ float part_x[4][DD];
    __shared__ float part_y[4][DD];
    __shared__ float s_l[NPP], s_r[NPP];
    __shared__ float xl[DD], yl[DD];
    __shared__ float h16[16][DD];
    __shared__ float hbuf[DD];
    __shared__ float regv[2];

    // ---------------- Phase A: gathers ----------------
    if (wave < 8) {
        // pooling waves: waves 0-3 -> x (16 rows each), waves 4-7 -> y
        const int* ids = (wave < 4) ? (x_id + b * NXX) : (y_id + b * NYY);
        const int base = (wave & 3) * 16;
        float4 m = make_float4(-INFINITY, -INFINITY, -INFINITY, -INFINITY);
        for (int c = 0; c < 2; ++c) {
            float4 v[8];
            #pragma unroll
            for (int i = 0; i < 8; ++i) {
                size_t row = (size_t)ids[base + c * 8 + i] * DD;
                v[i] = *reinterpret_cast<const float4*>(feat + row + lane * 4);
            }
            #pragma unroll
            for (int i = 0; i < 8; ++i) {
                m.x = fmaxf(m.x, v[i].x); m.y = fmaxf(m.y, v[i].y);
                m.z = fmaxf(m.z, v[i].z); m.w = fmaxf(m.w, v[i].w);
            }
        }
        float* dst = (wave < 4) ? &part_x[wave & 3][0] : &part_y[wave & 3][0];
        *reinterpret_cast<float4*>(dst + lane * 4) = m;
    } else {
        // attention waves: waves 8-11 -> plo (8 rows each), 12-15 -> pro
        const bool left = (wave < 12);
        const int* ids = (left ? plo_id : pro_id) + b * NPP;
        const float* wv = left ? w6w : w7w;
        const float bias = left ? w6b[0] : w7b[0];
        const float4 wreg = *reinterpret_cast<const float4*>(wv + lane * 4);
        const int rbase = (wave & 3) * 8;
        float4 v[8];
        #pragma unroll
        for (int i = 0; i < 8; ++i) {
            size_t row = (size_t)ids[rbase + i] * DD;
            v[i] = *reinterpret_cast<const float4*>(feat + row + lane * 4);
        }
        #pragma unroll
        for (int i = 0; i < 8; ++i) {
            float p = v[i].x * wreg.x + v[i].y * wreg.y +
                      v[i].z * wreg.z + v[i].w * wreg.w;
            p = wave_reduce_sum(p);
            if (lane == 0) (left ? s_l : s_r)[rbase + i] = p + bias;
        }
    }
    __syncthreads();

    // ---------------- Phase B: pool combine + softmax ----------------
    if (tid < DD) {
        float a   = fmaxf(fmaxf(part_x[0][tid], part_x[1][tid]),
                          fmaxf(part_x[2][tid], part_x[3][tid]));
        float bb2 = fmaxf(fmaxf(part_y[0][tid], part_y[1][tid]),
                          fmaxf(part_y[2][tid], part_y[3][tid]));
        xl[tid] = fabsf(a - bb2);
        yl[tid] = a * bb2;
        out[OUT_ARGC + b * DD + tid] = bb2;   // argc
    } else if (wave == 4 || wave == 5) {
        const float* s = (wave == 4) ? s_l : s_r;
        float v = (lane < NPP) ? s[lane] : -INFINITY;
        float mx = wave_reduce_max(v);
        float e = (lane < NPP) ? __expf(v - mx) : 0.0f;
        float denom = wave_reduce_sum(e);
        float at = e / denom;
        float sq = wave_reduce_sum(at * at);
        if (lane == 0) regv[wave - 4] = sq * (1.0f / NPP);
    }
    __syncthreads();

    if (tid == 0) {
        atomicAdd(out + OUT_REG, (regv[0] + regv[1]) * 0.5f * (1.0f / BB));
    }

    // ---------------- Phase C: MLP partial (x@W1 + y@W2) ----------------
    {
        const int jg = tid & 63;   // column group: 4 consecutive cols
        const int kk = tid >> 6;   // k slice: 16 k's
        float4 acc = make_float4(0.f, 0.f, 0.f, 0.f);
        #pragma unroll 4
        for (int k = kk * 16; k < kk * 16 + 16; ++k) {
            const float xk = xl[k], yk = yl[k];
            const float4 a1 = *reinterpret_cast<const float4*>(w1w + (size_t)k * DD + jg * 4);
            const float4 a2 = *reinterpret_cast<const float4*>(w2w + (size_t)k * DD + jg * 4);
            acc.x += xk * a1.x + yk * a2.x;
            acc.y += xk * a1.y + yk * a2.y;
            acc.z += xk * a1.z + yk * a2.z;
            acc.w += xk * a1.w + yk * a2.w;
        }
        *reinterpret_cast<float4*>(&h16[kk][jg * 4]) = acc;
    }
    __syncthreads();

    // ---------------- Phase D: bias + tanh ----------------
    if (tid < DD) {
        float pre = w1b[tid] + w2b[tid];
        #pragma unroll
        for (int i = 0; i < 16; ++i) pre += h16[i][tid];
        hbuf[tid] = tanhf(pre);
    }
    __syncthreads();

    // ---------------- Phase E: logits ----------------
    if (wave < 3) {
        float p = 0.0f;
        #pragma unroll
        for (int i = 0; i < 4; ++i) {
            int k = lane + i * 64;
            p += hbuf[k] * clsw[k * 3 + wave];
        }
        p = wave_reduce_sum(p);
        if (lane == 0) out[b * 3 + wave] = p + clsb[wave];
    }
}

extern "C" void kernel_launch(void* const* d_in, const int* in_sizes, int n_in,
                              void* d_out, int out_size, void* d_ws, size_t ws_size,
                              hipStream_t stream) {
    const float* feat   = (const float*)d_in[0];
    const int*   x_id   = (const int*)d_in[1];
    const int*   y_id   = (const int*)d_in[2];
    const int*   plo_id = (const int*)d_in[3];
    const int*   pro_id = (const int*)d_in[4];
    const float* w1w    = (const float*)d_in[5];
    const float* w1b    = (const float*)d_in[6];
    const float* w2w    = (const float*)d_in[7];
    const float* w2b    = (const float*)d_in[8];
    const float* w6w    = (const float*)d_in[9];
    const float* w6b    = (const float*)d_in[10];
    const float* w7w    = (const float*)d_in[11];
    const float* w7b    = (const float*)d_in[12];
    const float* clsw   = (const float*)d_in[13];
    const float* clsb   = (const float*)d_in[14];
    float* out = (float*)d_out;

    // zero the reg_loss accumulator slot (d_out is poisoned before every launch)
    hipMemsetAsync((char*)d_out + OUT_REG * sizeof(float), 0, sizeof(float), stream);

    hipLaunchKernelGGL(fused_graph_kernel, dim3(BB), dim3(1024), 0, stream,
                       feat, x_id, y_id, plo_id, pro_id,
                       w1w, w1b, w2w, w2b, w6w, w6b, w7w, w7b, clsw, clsb, out);
}